// Round 11
// baseline (56534.399 us; speedup 1.0000x reference)
//
#include <hip/hip_runtime.h>
#include <hip/hip_bf16.h>

#define S_LEN 2048
#define BATCH 64
#define HID   512
#define GATES 2048   // 4*HID
#define DIN   512

typedef __attribute__((ext_vector_type(8))) short short8v;
typedef __attribute__((ext_vector_type(4))) float f32x4;
typedef __attribute__((ext_vector_type(4))) unsigned uint4v;

__device__ inline unsigned short f2bf(float f) {
  union { float f; unsigned u; } a; a.f = f;
  unsigned r = a.u + 0x7fffu + ((a.u >> 16) & 1u);
  return (unsigned short)(r >> 16);
}
__device__ inline float bf2f(unsigned short h) {
  union { unsigned u; float f; } a; a.u = ((unsigned)h) << 16; return a.f;
}

// ---------- kernel 1: split x (fp32) -> bf16 hi + lo ----------
__global__ __launch_bounds__(256) void k_split_x(const float* __restrict__ x,
                                                 unsigned short* __restrict__ xhi,
                                                 unsigned short* __restrict__ xlo) {
  const long total = (long)S_LEN * BATCH * DIN / 4;
  long i = (long)blockIdx.x * blockDim.x + threadIdx.x;
  const long stride = (long)gridDim.x * blockDim.x;
  for (; i < total; i += stride) {
    float4 v = ((const float4*)x)[i];
    ushort4 hv, lv;
    hv.x = f2bf(v.x); lv.x = f2bf(v.x - bf2f(hv.x));
    hv.y = f2bf(v.y); lv.y = f2bf(v.y - bf2f(hv.y));
    hv.z = f2bf(v.z); lv.z = f2bf(v.z - bf2f(hv.z));
    hv.w = f2bf(v.w); lv.w = f2bf(v.w - bf2f(hv.w));
    ((ushort4*)xhi)[i] = hv;
    ((ushort4*)xlo)[i] = lv;
  }
}

// ---------- kernel 2: weights -> bf16, bias sum ----------
__global__ __launch_bounds__(256) void k_prep_w(const float* __restrict__ Wih,
                                                const float* __restrict__ Whh,
                                                const float* __restrict__ bih,
                                                const float* __restrict__ bhh,
                                                unsigned short* __restrict__ WihB,
                                                unsigned short* __restrict__ WhhB,
                                                float* __restrict__ bias) {
  int i = blockIdx.x * 256 + threadIdx.x;
  if (i < GATES * DIN) {
    WihB[i] = f2bf(Wih[i]);
    WhhB[i] = f2bf(Whh[i]);
  }
  if (i < GATES) bias[i] = bih[i] + bhh[i];
}

// ---------- kernel 3: pre[t][u][b][gate] = x[t,b,:]·Wih[gate*512+u,:] + biases ----------
#define BM 128
#define BN 128
#define BK 32
#define LDSROW 40

__global__ __launch_bounds__(256) void k_gemm_pre(
    const unsigned short* __restrict__ A,   // WihB [2048][512]
    const unsigned short* __restrict__ Bh,  // xhi  [131072][512]
    const unsigned short* __restrict__ Bl,  // xlo
    const float* __restrict__ bias,
    unsigned short* __restrict__ pre)       // [S][512 u][64 b][4 gate] bf16
{
  __shared__ unsigned short As [BM * LDSROW];
  __shared__ unsigned short Bhs[BM * LDSROW];
  __shared__ unsigned short Bls[BM * LDSROW];

  const int tid  = threadIdx.x;
  const int lane = tid & 63;
  const int wave = tid >> 6;
  const int bm = blockIdx.x & 15;
  const int bn = blockIdx.x >> 4;
  const int wr = wave >> 1, wc = wave & 1;

  f32x4 acc[4][4];
  #pragma unroll
  for (int i = 0; i < 4; ++i)
    #pragma unroll
    for (int j = 0; j < 4; ++j) acc[i][j] = (f32x4){0.f, 0.f, 0.f, 0.f};

  const long arow0 = (long)bm * BM;
  const long brow0 = (long)bn * BN;

  for (int kt = 0; kt < DIN / BK; ++kt) {
    #pragma unroll
    for (int it = 0; it < 2; ++it) {
      int c = tid + it * 256;
      int row = c >> 2, kc = c & 3;
      int lbyte = row * (LDSROW * 2) + kc * 16;
      long ga = (arow0 + row) * 512 + kt * BK + kc * 8;
      long gb = (brow0 + row) * 512 + kt * BK + kc * 8;
      *(short8v*)((char*)As  + lbyte) = *(const short8v*)(A  + ga);
      *(short8v*)((char*)Bhs + lbyte) = *(const short8v*)(Bh + gb);
      *(short8v*)((char*)Bls + lbyte) = *(const short8v*)(Bl + gb);
    }
    __syncthreads();

    short8v a[4], bh[4], bl[4];
    #pragma unroll
    for (int mt = 0; mt < 4; ++mt) {
      int r = wr * 64 + mt * 16 + (lane & 15);
      a[mt] = *(const short8v*)((const char*)As + r * (LDSROW * 2) + (lane >> 4) * 16);
    }
    #pragma unroll
    for (int nt = 0; nt < 4; ++nt) {
      int r = wc * 64 + nt * 16 + (lane & 15);
      bh[nt] = *(const short8v*)((const char*)Bhs + r * (LDSROW * 2) + (lane >> 4) * 16);
      bl[nt] = *(const short8v*)((const char*)Bls + r * (LDSROW * 2) + (lane >> 4) * 16);
    }
    #pragma unroll
    for (int mt = 0; mt < 4; ++mt)
      #pragma unroll
      for (int nt = 0; nt < 4; ++nt) {
        acc[mt][nt] = __builtin_amdgcn_mfma_f32_16x16x32_bf16(a[mt], bh[nt], acc[mt][nt], 0, 0, 0);
        acc[mt][nt] = __builtin_amdgcn_mfma_f32_16x16x32_bf16(a[mt], bl[nt], acc[mt][nt], 0, 0, 0);
      }
    __syncthreads();
  }

  #pragma unroll
  for (int mt = 0; mt < 4; ++mt) {
    #pragma unroll
    for (int j = 0; j < 4; ++j) {
      int m = bm * BM + wr * 64 + mt * 16 + (lane >> 4) * 4 + j;
      int gate = m >> 9;
      int u    = m & 511;
      float bv = bias[m];
      #pragma unroll
      for (int nt = 0; nt < 4; ++nt) {
        int n = bn * BN + wc * 64 + nt * 16 + (lane & 15);
        int t = n >> 6, b = n & 63;
        pre[(((long)t * 512 + u) * 64 + b) * 4 + gate] = f2bf(acc[mt][nt][j] + bv);
      }
    }
  }
}

// ---------- kernel 4: persistent recurrence, tagged self-publishing h ----------
// r10 substrate (swapped-MFMA, W_hh in LDS, swizzled ldsH, compiler AGENT atomics)
// with the flag sync REPLACED by tagged h words: u32 = (bf16(h)<<16) | step.
// A dword store is single-copy atomic -> the tag validates its own payload.
// Loop = poll+gather (ONE MALL RT, discovery merged with fetch) -> bar1 ->
// MFMA -> bar2 -> cell -> fire-and-forget tagged publish. No flags, no tail
// vmcnt(0) drain (which in r10 waited on prior HBM out-stores), no tail
// __syncthreads.
// WAR safety (per quad, the only sharing domain): my poll saw tag t on EVERY
// unit of my batch slice -> every quad block published t -> every reader of
// phase (t-1)&1 finished its gather -> my publish of t+1 into that phase is
// safe. In-block ldsH WAR is covered by barrier #2.
__global__ __launch_bounds__(256, 1) void k_lstm(
    const unsigned short* __restrict__ pre,   // [S][512][64][4] bf16
    const unsigned short* __restrict__ WhhB,  // [2048][512] bf16
    unsigned* __restrict__ hbuf,              // [2][64 b][512 u] u32 (h|tag)
    float* __restrict__ out)                  // [S*B*H | h_f | c_f]
{
  __shared__ char lds[49152];
  char* ldsW = lds;          // 32KB [ct:2][ks:16][ke:4][r:16][16B]
  char* ldsH = lds + 32768;  // 16KB [ke:4][b:16][slot:16][16B], slot=(ks^b)&15

  const int tid  = threadIdx.x;
  const int lane = tid & 63;
  const int wave = tid >> 6;          // 0..3
  const int q    = blockIdx.x >> 6;   // batch quad
  const int ublk = blockIdx.x & 63;   // unit octet

  // --- stage W tile into LDS: tile-row r -> (du = r>>2, gate = r&3) ---
  for (int c = tid; c < 2048; c += 256) {
    int ct2 = c >> 10, ks = (c >> 6) & 15, ke = (c >> 4) & 3, r = c & 15;
    long row = (long)(r & 3) * 512 + ublk * 8 + ct2 * 4 + (r >> 2);
    *(short8v*)(ldsW + c * 16) =
        *(const short8v*)(WhhB + row * 512 + ks * 32 + ke * 8);
  }
  __syncthreads();

  // gather assignment: thread stages h[q*16+gb][useg*32 .. +32) (tagged u32s)
  const int gb   = tid >> 4;          // 0..15 (batch row staged)
  const int useg = tid & 15;          // 0..15 (== ks staged)

  // cell assignment (waves 0,1): one cell per lane
  const int ct  = wave;
  const int b_c = lane & 15;
  const int duc = lane >> 4;
  const int b_g = q * 16 + b_c;
  const int u_g = ublk * 8 + ct * 4 + duc;

  float cst = 0.f;
  float heat = (float)tid * 1e-3f + 1.0f;

  #pragma unroll 1
  for (int t = 0; t < S_LEN; ++t) {
    // x-gates (8B, i/f/g/o contiguous) — issued before the poll, hides under it
    ushort4 pv = (ushort4){0, 0, 0, 0};
    if (wave < 2)
      pv = *(const ushort4*)(pre + (((long)t * 512 + u_g) * 64 + b_g) * 4);

    if (t > 0) {
      // poll-on-data: 32 tagged u32 agent-atomic loads; retry until all == t
      const unsigned* hb = hbuf + (t & 1) * (64 * 512) + (q * 16 + gb) * 512 + useg * 32;
      const unsigned tg = (unsigned)t & 0xffffu;
      unsigned w[32];
      while (true) {
        #pragma unroll
        for (int j = 0; j < 32; ++j)
          w[j] = __hip_atomic_load(hb + j, __ATOMIC_RELAXED, __HIP_MEMORY_SCOPE_AGENT);
        unsigned bad = 0;
        #pragma unroll
        for (int j = 0; j < 32; ++j) bad |= (w[j] ^ tg) & 0xffffu;
        if (__all(bad == 0)) break;
        #pragma unroll
        for (int z = 0; z < 8; ++z) heat = __builtin_fmaf(heat, 1.000001f, 1e-6f);
        asm volatile("" : "+v"(heat));
      }
      // pack hi16 payloads -> bf16-pair dwords; 4 swizzled b128 LDS writes
      char* hp = ldsH + gb * 256 + ((useg ^ gb) & 15) * 16;
      #pragma unroll
      for (int ke = 0; ke < 4; ++ke) {
        uint4v dv;
        #pragma unroll
        for (int j = 0; j < 4; ++j)
          dv[j] = (w[ke * 8 + 2 * j] >> 16) | (w[ke * 8 + 2 * j + 1] & 0xffff0000u);
        *(uint4v*)(hp + ke * 4096) = dv;
      }
    }

    // barrier #1: H tile ready (LDS-only drain)
    asm volatile("s_waitcnt lgkmcnt(0)" ::: "memory");
    __builtin_amdgcn_s_barrier();
    __builtin_amdgcn_sched_barrier(0);

    f32x4 sum = (f32x4){0.f, 0.f, 0.f, 0.f};
    if (wave < 2) {
      if (t > 0) {
        f32x4 e0 = sum, e1 = sum;
        const char* wa = ldsW + ct * 16384 + (lane >> 4) * 256 + (lane & 15) * 16;
        const char* ha = ldsH + (lane >> 4) * 4096 + (lane & 15) * 256;
        const int bcol = lane & 15;
        #pragma unroll
        for (int ks = 0; ks < 16; ++ks) {
          short8v av = *(const short8v*)(wa + ks * 1024);               // W (A-op)
          short8v bv = *(const short8v*)(ha + ((ks ^ bcol) & 15) * 16); // h (B-op)
          if (ks & 1) e1 = __builtin_amdgcn_mfma_f32_16x16x32_bf16(av, bv, e1, 0, 0, 0);
          else        e0 = __builtin_amdgcn_mfma_f32_16x16x32_bf16(av, bv, e0, 0, 0, 0);
        }
        sum = e0 + e1;
      }
    } else {
      // heater: keep CU activity up during the MFMA phase (cheap insurance)
      #pragma unroll
      for (int z = 0; z < 128; ++z) heat = __builtin_fmaf(heat, 1.0000001f, 1e-7f);
      asm volatile("" : "+v"(heat));
    }

    // barrier #2: all ldsH reads of step t done -> t+1 staging may overwrite
    asm volatile("s_waitcnt lgkmcnt(0)" ::: "memory");
    __builtin_amdgcn_s_barrier();
    __builtin_amdgcn_sched_barrier(0);

    if (wave < 2) {
      // cell update fully in-register: sum[0..3] = (i,f,g,o)
      float zi = sum[0] + bf2f(pv.x);
      float zf = sum[1] + bf2f(pv.y);
      float zg = sum[2] + bf2f(pv.z);
      float zo = sum[3] + bf2f(pv.w);
      float ii = 1.f / (1.f + __expf(-zi));
      float ff = 1.f / (1.f + __expf(-zf));
      float e1x = __expf(2.f * fminf(zg, 15.f));
      float gg = (e1x - 1.f) / (e1x + 1.f);
      float oo = 1.f / (1.f + __expf(-zo));
      float cn = ff * cst + ii * gg;
      float e2x = __expf(2.f * fminf(cn, 15.f));
      float tc = (e2x - 1.f) / (e2x + 1.f);
      float hv = oo * tc;
      cst = cn;

      // fire-and-forget tagged publish: payload + tag in one atomic dword
      unsigned hw = ((unsigned)f2bf(hv) << 16) | ((unsigned)(t + 1) & 0xffffu);
      __hip_atomic_store(hbuf + ((t + 1) & 1) * (64 * 512) + b_g * 512 + u_g,
                         hw, __ATOMIC_RELAXED, __HIP_MEMORY_SCOPE_AGENT);

      // out stores off the critical path (never drained in-loop)
      out[(long)t * (BATCH * HID) + (long)b_g * HID + u_g] = hv;
      if (t == S_LEN - 1) {
        long fb = (long)S_LEN * (BATCH * HID);
        out[fb + (long)b_g * HID + u_g] = hv;
        out[fb + BATCH * HID + (long)b_g * HID + u_g] = cn;
      }
    }
  }
}

extern "C" void kernel_launch(void* const* d_in, const int* in_sizes, int n_in,
                              void* d_out, int out_size, void* d_ws, size_t ws_size,
                              hipStream_t stream) {
  const float* x   = (const float*)d_in[0];
  const float* Wih = (const float*)d_in[1];
  const float* Whh = (const float*)d_in[2];
  const float* bih = (const float*)d_in[3];
  const float* bhh = (const float*)d_in[4];
  float* out = (float*)d_out;

  char* ws = (char*)d_ws;
  size_t off = 0;
  auto alloc = [&](size_t bytes) -> char* {
    char* p = ws + off;
    off += (bytes + 255) & ~(size_t)255;
    return p;
  };
  unsigned short* xhi  = (unsigned short*)alloc((size_t)S_LEN * BATCH * DIN * 2);
  unsigned short* xlo  = (unsigned short*)alloc((size_t)S_LEN * BATCH * DIN * 2);
  unsigned short* preb = (unsigned short*)alloc((size_t)S_LEN * GATES * BATCH * 2);
  unsigned short* WihB = (unsigned short*)alloc((size_t)GATES * DIN * 2);
  unsigned short* WhhB = (unsigned short*)alloc((size_t)GATES * DIN * 2);
  float*          bias = (float*)alloc((size_t)GATES * 4);
  unsigned*       hbuf = (unsigned*)alloc((size_t)2 * BATCH * HID * 4);  // 256KB tagged

  // tags must be cleared every launch/replay (step tags would alias otherwise)
  hipMemsetAsync(hbuf, 0, (size_t)2 * BATCH * HID * 4, stream);
  k_split_x<<<8192, 256, 0, stream>>>(x, xhi, xlo);
  k_prep_w<<<4096, 256, 0, stream>>>(Wih, Whh, bih, bhh, WihB, WhhB, bias);
  k_gemm_pre<<<16384, 256, 0, stream>>>(WihB, xhi, xlo, bias, preb);
  k_lstm<<<256, 256, 0, stream>>>(preb, WhhB, hbuf, out);
}

// Round 12
// 37424.393 us; speedup vs baseline: 1.5106x; 1.5106x over previous
//
#include <hip/hip_runtime.h>
#include <hip/hip_bf16.h>

#define S_LEN 2048
#define BATCH 64
#define HID   512
#define GATES 2048   // 4*HID
#define DIN   512

typedef __attribute__((ext_vector_type(8))) short short8v;
typedef __attribute__((ext_vector_type(4))) float f32x4;
typedef __attribute__((ext_vector_type(4))) unsigned uint4v;

__device__ inline unsigned short f2bf(float f) {
  union { float f; unsigned u; } a; a.f = f;
  unsigned r = a.u + 0x7fffu + ((a.u >> 16) & 1u);
  return (unsigned short)(r >> 16);
}
__device__ inline float bf2f(unsigned short h) {
  union { unsigned u; float f; } a; a.u = ((unsigned)h) << 16; return a.f;
}

// ---------- kernel 1: split x (fp32) -> bf16 hi + lo ----------
__global__ __launch_bounds__(256) void k_split_x(const float* __restrict__ x,
                                                 unsigned short* __restrict__ xhi,
                                                 unsigned short* __restrict__ xlo) {
  const long total = (long)S_LEN * BATCH * DIN / 4;
  long i = (long)blockIdx.x * blockDim.x + threadIdx.x;
  const long stride = (long)gridDim.x * blockDim.x;
  for (; i < total; i += stride) {
    float4 v = ((const float4*)x)[i];
    ushort4 hv, lv;
    hv.x = f2bf(v.x); lv.x = f2bf(v.x - bf2f(hv.x));
    hv.y = f2bf(v.y); lv.y = f2bf(v.y - bf2f(hv.y));
    hv.z = f2bf(v.z); lv.z = f2bf(v.z - bf2f(hv.z));
    hv.w = f2bf(v.w); lv.w = f2bf(v.w - bf2f(hv.w));
    ((ushort4*)xhi)[i] = hv;
    ((ushort4*)xlo)[i] = lv;
  }
}

// ---------- kernel 2: weights -> bf16, bias sum ----------
__global__ __launch_bounds__(256) void k_prep_w(const float* __restrict__ Wih,
                                                const float* __restrict__ Whh,
                                                const float* __restrict__ bih,
                                                const float* __restrict__ bhh,
                                                unsigned short* __restrict__ WihB,
                                                unsigned short* __restrict__ WhhB,
                                                float* __restrict__ bias) {
  int i = blockIdx.x * 256 + threadIdx.x;
  if (i < GATES * DIN) {
    WihB[i] = f2bf(Wih[i]);
    WhhB[i] = f2bf(Whh[i]);
  }
  if (i < GATES) bias[i] = bih[i] + bhh[i];
}

// ---------- kernel 3: pre[t][u][b][gate] = x[t,b,:]·Wih[gate*512+u,:] + biases ----------
#define BM 128
#define BN 128
#define BK 32
#define LDSROW 40

__global__ __launch_bounds__(256) void k_gemm_pre(
    const unsigned short* __restrict__ A,   // WihB [2048][512]
    const unsigned short* __restrict__ Bh,  // xhi  [131072][512]
    const unsigned short* __restrict__ Bl,  // xlo
    const float* __restrict__ bias,
    unsigned short* __restrict__ pre)       // [S][512 u][64 b][4 gate] bf16
{
  __shared__ unsigned short As [BM * LDSROW];
  __shared__ unsigned short Bhs[BM * LDSROW];
  __shared__ unsigned short Bls[BM * LDSROW];

  const int tid  = threadIdx.x;
  const int lane = tid & 63;
  const int wave = tid >> 6;
  const int bm = blockIdx.x & 15;
  const int bn = blockIdx.x >> 4;
  const int wr = wave >> 1, wc = wave & 1;

  f32x4 acc[4][4];
  #pragma unroll
  for (int i = 0; i < 4; ++i)
    #pragma unroll
    for (int j = 0; j < 4; ++j) acc[i][j] = (f32x4){0.f, 0.f, 0.f, 0.f};

  const long arow0 = (long)bm * BM;
  const long brow0 = (long)bn * BN;

  for (int kt = 0; kt < DIN / BK; ++kt) {
    #pragma unroll
    for (int it = 0; it < 2; ++it) {
      int c = tid + it * 256;
      int row = c >> 2, kc = c & 3;
      int lbyte = row * (LDSROW * 2) + kc * 16;
      long ga = (arow0 + row) * 512 + kt * BK + kc * 8;
      long gb = (brow0 + row) * 512 + kt * BK + kc * 8;
      *(short8v*)((char*)As  + lbyte) = *(const short8v*)(A  + ga);
      *(short8v*)((char*)Bhs + lbyte) = *(const short8v*)(Bh + gb);
      *(short8v*)((char*)Bls + lbyte) = *(const short8v*)(Bl + gb);
    }
    __syncthreads();

    short8v a[4], bh[4], bl[4];
    #pragma unroll
    for (int mt = 0; mt < 4; ++mt) {
      int r = wr * 64 + mt * 16 + (lane & 15);
      a[mt] = *(const short8v*)((const char*)As + r * (LDSROW * 2) + (lane >> 4) * 16);
    }
    #pragma unroll
    for (int nt = 0; nt < 4; ++nt) {
      int r = wc * 64 + nt * 16 + (lane & 15);
      bh[nt] = *(const short8v*)((const char*)Bhs + r * (LDSROW * 2) + (lane >> 4) * 16);
      bl[nt] = *(const short8v*)((const char*)Bls + r * (LDSROW * 2) + (lane >> 4) * 16);
    }
    #pragma unroll
    for (int mt = 0; mt < 4; ++mt)
      #pragma unroll
      for (int nt = 0; nt < 4; ++nt) {
        acc[mt][nt] = __builtin_amdgcn_mfma_f32_16x16x32_bf16(a[mt], bh[nt], acc[mt][nt], 0, 0, 0);
        acc[mt][nt] = __builtin_amdgcn_mfma_f32_16x16x32_bf16(a[mt], bl[nt], acc[mt][nt], 0, 0, 0);
      }
    __syncthreads();
  }

  #pragma unroll
  for (int mt = 0; mt < 4; ++mt) {
    #pragma unroll
    for (int j = 0; j < 4; ++j) {
      int m = bm * BM + wr * 64 + mt * 16 + (lane >> 4) * 4 + j;
      int gate = m >> 9;
      int u    = m & 511;
      float bv = bias[m];
      #pragma unroll
      for (int nt = 0; nt < 4; ++nt) {
        int n = bn * BN + wc * 64 + nt * 16 + (lane & 15);
        int t = n >> 6, b = n & 63;
        pre[(((long)t * 512 + u) * 64 + b) * 4 + gate] = f2bf(acc[mt][nt][j] + bv);
      }
    }
  }
}

// ---------- kernel 4: persistent recurrence, role-split waves ----------
// 256 blocks x 256 threads. Quad q = bid>>6 owns batches [q*16,+16); ublk owns
// units [ublk*8,+8). r10 economics (flag discovery 1 dword/lane + ONE-SHOT bulk
// gather via compiler AGENT atomics — the measured-fast path) with the publish
// path de-serialized:
//  * h words tagged ((bf16<<16)|step): flag becomes a HINT. Publisher fires h
//    stores then per-WAVE flag stores with NO vmcnt drain and NO __syncthreads;
//    readers validate tags on the one-shot gather and retry only in the rare
//    store-reorder window. (hbuf memset per launch -> no cross-replay aliasing.)
//  * waves 2-3 own ALL HBM traffic: prefetch pre[t+1] -> LDS, and issue step
//    t-1's out stores from an LDS handoff. Worker waves 0-1 touch only MALL
//    (gather/publish/flags) -> their implicit vmcnt waits never include ~900cy
//    HBM latency (r10's hidden drain).
// MFMA/LDS layout byte-identical to r10/r11 (refcheck-passed, 0 bank conflicts).
__global__ __launch_bounds__(256, 1) void k_lstm(
    const unsigned short* __restrict__ pre,   // [S][512][64][4] bf16
    const unsigned short* __restrict__ WhhB,  // [2048][512] bf16
    unsigned* __restrict__ hbuf,              // [2][64 b][512 u] u32 (h|tag)
    unsigned* __restrict__ flags,             // [2 pubwave][4][64]
    float* __restrict__ out)                  // [S*B*H | h_f | c_f]
{
  __shared__ char lds[52224];
  char*  ldsW  = lds;                    // 32KB [ct:2][ks:16][ke:4][r:16][16B]
  char*  ldsH  = lds + 32768;            // 16KB [ke:4][b:16][slot:16][16B], slot=(ks^b)&15
  char*  ldsPv = lds + 49152;            // 2KB  [phase:2][cell:128][8B]
  float* ldsO  = (float*)(lds + 51200);  // 1KB  [phase:2][cell:128] f32

  const int tid  = threadIdx.x;
  const int lane = tid & 63;
  const int wave = tid >> 6;          // 0..3
  const int q    = blockIdx.x >> 6;   // batch quad
  const int ublk = blockIdx.x & 63;   // unit octet

  // --- stage W tile into LDS: tile-row r -> (du = r>>2, gate = r&3) ---
  for (int c = tid; c < 2048; c += 256) {
    int ct2 = c >> 10, ks = (c >> 6) & 15, ke = (c >> 4) & 3, r = c & 15;
    long row = (long)(r & 3) * 512 + ublk * 8 + ct2 * 4 + (r >> 2);
    *(short8v*)(ldsW + c * 16) =
        *(const short8v*)(WhhB + row * 512 + ks * 32 + ke * 8);
  }
  // prologue: waves 2-3 preload pre[0] slice into ldsPv phase 0
  if (wave >= 2) {
    int t2 = tid - 128;                 // 0..127: cu = t2&7, cb = t2>>3
    ushort4 x = *(const ushort4*)(pre +
        (((long)0 * 512 + ublk * 8 + (t2 & 7)) * 64 + q * 16 + (t2 >> 3)) * 4);
    *(ushort4*)(ldsPv + t2 * 8) = x;
  }
  __syncthreads();

  // gather assignment: thread stages h[q*16+gb][useg*32 .. +32) (tagged u32s)
  const int gb   = tid >> 4;          // 0..15 (batch row staged)
  const int useg = tid & 15;          // 0..15 (== ks staged)

  // worker cell assignment (waves 0,1): one cell per lane
  const int ct   = wave;
  const int b_c  = lane & 15;
  const int duc  = lane >> 4;
  const int b_g  = q * 16 + b_c;
  const int u_g  = ublk * 8 + ct * 4 + duc;
  const int cell = b_c * 8 + ct * 4 + duc;   // linear cell id (matches t2 map)

  float cst = 0.f, hv = 0.f, cn = 0.f;
  float heat = (float)tid * 1e-3f + 1.0f;

  #pragma unroll 1
  for (int t = 0; t < S_LEN; ++t) {
    if (t > 0) {
      // discovery: 2 per-wave flag arrays, 1 dword/lane each (cheap hint)
      {
        const unsigned* f0 = flags + q * 64 + lane;
        const unsigned* f1 = flags + 256 + q * 64 + lane;
        while (true) {
          unsigned v0 = __hip_atomic_load(f0, __ATOMIC_RELAXED, __HIP_MEMORY_SCOPE_AGENT);
          unsigned v1 = __hip_atomic_load(f1, __ATOMIC_RELAXED, __HIP_MEMORY_SCOPE_AGENT);
          if (__all(v0 >= (unsigned)t && v1 >= (unsigned)t)) break;
          #pragma unroll
          for (int z = 0; z < 8; ++z) heat = __builtin_fmaf(heat, 1.000001f, 1e-6f);
          asm volatile("" : "+v"(heat));
        }
      }
      asm volatile("" ::: "memory");
      // one-shot bulk gather, tag-validated (retry only on store reorder)
      const unsigned* hb = hbuf + (t & 1) * (64 * 512) + (q * 16 + gb) * 512 + useg * 32;
      const unsigned tg = (unsigned)t & 0xffffu;
      unsigned w[32];
      while (true) {
        #pragma unroll
        for (int j = 0; j < 32; ++j)
          w[j] = __hip_atomic_load(hb + j, __ATOMIC_RELAXED, __HIP_MEMORY_SCOPE_AGENT);
        unsigned bad = 0;
        #pragma unroll
        for (int j = 0; j < 32; ++j) bad |= (w[j] ^ tg) & 0xffffu;
        if (__all(bad == 0)) break;
      }
      // pack hi16 payloads -> bf16-pair dwords; 4 swizzled b128 LDS writes
      char* hp = ldsH + gb * 256 + ((useg ^ gb) & 15) * 16;
      #pragma unroll
      for (int ke = 0; ke < 4; ++ke) {
        uint4v dv;
        #pragma unroll
        for (int j = 0; j < 4; ++j)
          dv[j] = (w[ke * 8 + 2 * j] >> 16) | (w[ke * 8 + 2 * j + 1] & 0xffff0000u);
        *(uint4v*)(hp + ke * 4096) = dv;
      }
    }

    // barrier #1: H tile + ldsO/ldsPv handoffs visible (LDS-only drain)
    asm volatile("s_waitcnt lgkmcnt(0)" ::: "memory");
    __builtin_amdgcn_s_barrier();
    __builtin_amdgcn_sched_barrier(0);

    f32x4 sum = (f32x4){0.f, 0.f, 0.f, 0.f};
    ushort4 pv = (ushort4){0, 0, 0, 0};
    if (wave < 2) {
      pv = *(const ushort4*)(ldsPv + ((t & 1) * 128 + cell) * 8);
      if (t > 0) {
        f32x4 e0 = sum, e1 = sum;
        const char* wa = ldsW + ct * 16384 + (lane >> 4) * 256 + (lane & 15) * 16;
        const char* ha = ldsH + (lane >> 4) * 4096 + (lane & 15) * 256;
        const int bcol = lane & 15;
        #pragma unroll
        for (int ks = 0; ks < 16; ++ks) {
          short8v av = *(const short8v*)(wa + ks * 1024);               // W (A-op)
          short8v bv = *(const short8v*)(ha + ((ks ^ bcol) & 15) * 16); // h (B-op)
          if (ks & 1) e1 = __builtin_amdgcn_mfma_f32_16x16x32_bf16(av, bv, e1, 0, 0, 0);
          else        e0 = __builtin_amdgcn_mfma_f32_16x16x32_bf16(av, bv, e0, 0, 0, 0);
        }
        sum = e0 + e1;
      }
    } else {
      // HBM service wave: out stores for step t-1 (LDS handoff) + pre[t+1] prefetch
      int t2 = tid - 128;
      if (t > 0) {
        float ov = ldsO[((t - 1) & 1) * 128 + t2];
        out[(long)(t - 1) * (BATCH * HID)
            + (long)(q * 16 + (t2 >> 3)) * HID + ublk * 8 + (t2 & 7)] = ov;
      }
      if (t + 1 < S_LEN) {
        ushort4 x = *(const ushort4*)(pre +
            (((long)(t + 1) * 512 + ublk * 8 + (t2 & 7)) * 64 + q * 16 + (t2 >> 3)) * 4);
        *(ushort4*)(ldsPv + (((t + 1) & 1) * 128 + t2) * 8) = x;
      }
    }

    // barrier #2: ldsH reads done (next staging may overwrite); pv phase reads done
    asm volatile("s_waitcnt lgkmcnt(0)" ::: "memory");
    __builtin_amdgcn_s_barrier();
    __builtin_amdgcn_sched_barrier(0);

    if (wave < 2) {
      // cell update fully in-register: sum[0..3] = (i,f,g,o)
      float zi = sum[0] + bf2f(pv.x);
      float zf = sum[1] + bf2f(pv.y);
      float zg = sum[2] + bf2f(pv.z);
      float zo = sum[3] + bf2f(pv.w);
      float ii = 1.f / (1.f + __expf(-zi));
      float ff = 1.f / (1.f + __expf(-zf));
      float e1x = __expf(2.f * fminf(zg, 15.f));
      float gg = (e1x - 1.f) / (e1x + 1.f);
      float oo = 1.f / (1.f + __expf(-zo));
      cn = ff * cst + ii * gg;
      float e2x = __expf(2.f * fminf(cn, 15.f));
      float tc = (e2x - 1.f) / (e2x + 1.f);
      hv = oo * tc;
      cst = cn;

      // handoff for the out-store wave (read next step after bar1)
      ldsO[(t & 1) * 128 + cell] = hv;

      // tagged publish (fire-and-forget) then per-wave flag — NO drain/barrier
      unsigned hw = ((unsigned)f2bf(hv) << 16) | ((unsigned)(t + 1) & 0xffffu);
      __hip_atomic_store(hbuf + ((t + 1) & 1) * (64 * 512) + b_g * 512 + u_g,
                         hw, __ATOMIC_RELAXED, __HIP_MEMORY_SCOPE_AGENT);
      if (lane == 0)
        __hip_atomic_store(flags + wave * 256 + q * 64 + ublk, (unsigned)(t + 1),
                           __ATOMIC_RELAXED, __HIP_MEMORY_SCOPE_AGENT);
    }
  }

  // epilogue: last step's out row + final h/c
  asm volatile("s_waitcnt lgkmcnt(0)" ::: "memory");
  __builtin_amdgcn_s_barrier();
  if (wave >= 2) {
    int t2 = tid - 128;
    float ov = ldsO[((S_LEN - 1) & 1) * 128 + t2];
    out[(long)(S_LEN - 1) * (BATCH * HID)
        + (long)(q * 16 + (t2 >> 3)) * HID + ublk * 8 + (t2 & 7)] = ov;
  } else {
    long fb = (long)S_LEN * (BATCH * HID);
    out[fb + (long)b_g * HID + u_g] = hv;
    out[fb + BATCH * HID + (long)b_g * HID + u_g] = cn;
  }
}

extern "C" void kernel_launch(void* const* d_in, const int* in_sizes, int n_in,
                              void* d_out, int out_size, void* d_ws, size_t ws_size,
                              hipStream_t stream) {
  const float* x   = (const float*)d_in[0];
  const float* Wih = (const float*)d_in[1];
  const float* Whh = (const float*)d_in[2];
  const float* bih = (const float*)d_in[3];
  const float* bhh = (const float*)d_in[4];
  float* out = (float*)d_out;

  char* ws = (char*)d_ws;
  size_t off = 0;
  auto alloc = [&](size_t bytes) -> char* {
    char* p = ws + off;
    off += (bytes + 255) & ~(size_t)255;
    return p;
  };
  unsigned short* xhi  = (unsigned short*)alloc((size_t)S_LEN * BATCH * DIN * 2);
  unsigned short* xlo  = (unsigned short*)alloc((size_t)S_LEN * BATCH * DIN * 2);
  unsigned short* preb = (unsigned short*)alloc((size_t)S_LEN * GATES * BATCH * 2);
  unsigned short* WihB = (unsigned short*)alloc((size_t)GATES * DIN * 2);
  unsigned short* WhhB = (unsigned short*)alloc((size_t)GATES * DIN * 2);
  float*          bias = (float*)alloc((size_t)GATES * 4);
  unsigned*       hbuf = (unsigned*)alloc((size_t)2 * BATCH * HID * 4);  // 256KB tagged
  unsigned*       flg  = (unsigned*)alloc((size_t)2 * 256 * 4);          // 2KB

  // replay-safe: clear tags + flags every launch
  hipMemsetAsync(hbuf, 0, (size_t)2 * BATCH * HID * 4, stream);
  hipMemsetAsync(flg, 0, (size_t)2 * 256 * 4, stream);
  k_split_x<<<8192, 256, 0, stream>>>(x, xhi, xlo);
  k_prep_w<<<4096, 256, 0, stream>>>(Wih, Whh, bih, bhh, WihB, WhhB, bias);
  k_gemm_pre<<<16384, 256, 0, stream>>>(WihB, xhi, xlo, bias, preb);
  k_lstm<<<256, 256, 0, stream>>>(preb, WhhB, hbuf, flg, out);
}

// Round 14
// 15612.511 us; speedup vs baseline: 3.6211x; 2.3971x over previous
//
#include <hip/hip_runtime.h>
#include <hip/hip_bf16.h>

#define S_LEN 2048
#define BATCH 64
#define HID   512
#define GATES 2048   // 4*HID
#define DIN   512

typedef __attribute__((ext_vector_type(8))) short short8v;
typedef __attribute__((ext_vector_type(4))) float f32x4;
typedef __attribute__((ext_vector_type(4))) unsigned uint4v;

__device__ inline unsigned short f2bf(float f) {
  union { float f; unsigned u; } a; a.f = f;
  unsigned r = a.u + 0x7fffu + ((a.u >> 16) & 1u);
  return (unsigned short)(r >> 16);
}
__device__ inline float bf2f(unsigned short h) {
  union { unsigned u; float f; } a; a.u = ((unsigned)h) << 16; return a.f;
}

// ---------- kernel 1: split x (fp32) -> bf16 hi + lo ----------
__global__ __launch_bounds__(256) void k_split_x(const float* __restrict__ x,
                                                 unsigned short* __restrict__ xhi,
                                                 unsigned short* __restrict__ xlo) {
  const long total = (long)S_LEN * BATCH * DIN / 4;
  long i = (long)blockIdx.x * blockDim.x + threadIdx.x;
  const long stride = (long)gridDim.x * blockDim.x;
  for (; i < total; i += stride) {
    float4 v = ((const float4*)x)[i];
    ushort4 hv, lv;
    hv.x = f2bf(v.x); lv.x = f2bf(v.x - bf2f(hv.x));
    hv.y = f2bf(v.y); lv.y = f2bf(v.y - bf2f(hv.y));
    hv.z = f2bf(v.z); lv.z = f2bf(v.z - bf2f(hv.z));
    hv.w = f2bf(v.w); lv.w = f2bf(v.w - bf2f(hv.w));
    ((ushort4*)xhi)[i] = hv;
    ((ushort4*)xlo)[i] = lv;
  }
}

// ---------- kernel 2: weights -> bf16, bias sum ----------
__global__ __launch_bounds__(256) void k_prep_w(const float* __restrict__ Wih,
                                                const float* __restrict__ Whh,
                                                const float* __restrict__ bih,
                                                const float* __restrict__ bhh,
                                                unsigned short* __restrict__ WihB,
                                                unsigned short* __restrict__ WhhB,
                                                float* __restrict__ bias) {
  int i = blockIdx.x * 256 + threadIdx.x;
  if (i < GATES * DIN) {
    WihB[i] = f2bf(Wih[i]);
    WhhB[i] = f2bf(Whh[i]);
  }
  if (i < GATES) bias[i] = bih[i] + bhh[i];
}

// ---------- kernel 3: pre[t][u][b][gate] = x[t,b,:]·Wih[gate*512+u,:] + biases ----------
#define BM 128
#define BN 128
#define BK 32
#define LDSROW 40

__global__ __launch_bounds__(256) void k_gemm_pre(
    const unsigned short* __restrict__ A,   // WihB [2048][512]
    const unsigned short* __restrict__ Bh,  // xhi  [131072][512]
    const unsigned short* __restrict__ Bl,  // xlo
    const float* __restrict__ bias,
    unsigned short* __restrict__ pre)       // [S][512 u][64 b][4 gate] bf16
{
  __shared__ unsigned short As [BM * LDSROW];
  __shared__ unsigned short Bhs[BM * LDSROW];
  __shared__ unsigned short Bls[BM * LDSROW];

  const int tid  = threadIdx.x;
  const int lane = tid & 63;
  const int wave = tid >> 6;
  const int bm = blockIdx.x & 15;
  const int bn = blockIdx.x >> 4;
  const int wr = wave >> 1, wc = wave & 1;

  f32x4 acc[4][4];
  #pragma unroll
  for (int i = 0; i < 4; ++i)
    #pragma unroll
    for (int j = 0; j < 4; ++j) acc[i][j] = (f32x4){0.f, 0.f, 0.f, 0.f};

  const long arow0 = (long)bm * BM;
  const long brow0 = (long)bn * BN;

  for (int kt = 0; kt < DIN / BK; ++kt) {
    #pragma unroll
    for (int it = 0; it < 2; ++it) {
      int c = tid + it * 256;
      int row = c >> 2, kc = c & 3;
      int lbyte = row * (LDSROW * 2) + kc * 16;
      long ga = (arow0 + row) * 512 + kt * BK + kc * 8;
      long gb = (brow0 + row) * 512 + kt * BK + kc * 8;
      *(short8v*)((char*)As  + lbyte) = *(const short8v*)(A  + ga);
      *(short8v*)((char*)Bhs + lbyte) = *(const short8v*)(Bh + gb);
      *(short8v*)((char*)Bls + lbyte) = *(const short8v*)(Bl + gb);
    }
    __syncthreads();

    short8v a[4], bh[4], bl[4];
    #pragma unroll
    for (int mt = 0; mt < 4; ++mt) {
      int r = wr * 64 + mt * 16 + (lane & 15);
      a[mt] = *(const short8v*)((const char*)As + r * (LDSROW * 2) + (lane >> 4) * 16);
    }
    #pragma unroll
    for (int nt = 0; nt < 4; ++nt) {
      int r = wc * 64 + nt * 16 + (lane & 15);
      bh[nt] = *(const short8v*)((const char*)Bhs + r * (LDSROW * 2) + (lane >> 4) * 16);
      bl[nt] = *(const short8v*)((const char*)Bls + r * (LDSROW * 2) + (lane >> 4) * 16);
    }
    #pragma unroll
    for (int mt = 0; mt < 4; ++mt)
      #pragma unroll
      for (int nt = 0; nt < 4; ++nt) {
        acc[mt][nt] = __builtin_amdgcn_mfma_f32_16x16x32_bf16(a[mt], bh[nt], acc[mt][nt], 0, 0, 0);
        acc[mt][nt] = __builtin_amdgcn_mfma_f32_16x16x32_bf16(a[mt], bl[nt], acc[mt][nt], 0, 0, 0);
      }
    __syncthreads();
  }

  #pragma unroll
  for (int mt = 0; mt < 4; ++mt) {
    #pragma unroll
    for (int j = 0; j < 4; ++j) {
      int m = bm * BM + wr * 64 + mt * 16 + (lane >> 4) * 4 + j;
      int gate = m >> 9;
      int u    = m & 511;
      float bv = bias[m];
      #pragma unroll
      for (int nt = 0; nt < 4; ++nt) {
        int n = bn * BN + wc * 64 + nt * 16 + (lane & 15);
        int t = n >> 6, b = n & 63;
        pre[(((long)t * 512 + u) * 64 + b) * 4 + gate] = f2bf(acc[mt][nt][j] + bv);
      }
    }
  }
}

// ---------- kernel 4: persistent recurrence, big blocks, verified-gather ----------
// r13 structure (64 blocks x 512 threads, 8 gate-complete tiles, W_hh 128KB in
// LDS, swizzled ldsH, flags after vmcnt-drain+syncthreads) + the r13 race fix:
// h words are TAGGED ((bf16<<16)|step, single-copy-atomic dword). The flag is
// fast discovery; the one-shot gather VALIDATES tags and retries on mismatch.
// r13 showed the drained flag can rarely beat some h packets to visibility
// (fabric doesn't order across addresses); validation converts that silent
// race into a bounded retry. Steady state: validation passes first try (flag
// was drained), so cost = r13 + tag bytes. hbuf memset per launch (replay tag
// aliasing); mid-run per-location coherence prevents stale-tag acceptance.
__global__ __launch_bounds__(512, 1) void k_lstm(
    const unsigned short* __restrict__ pre,   // [S][512][64][4] bf16
    const unsigned short* __restrict__ WhhB,  // [2048][512] bf16
    unsigned* __restrict__ hbuf,              // [2][64 b][512 u] u32 (h|tag)
    unsigned* __restrict__ flags,             // [4][16]
    float* __restrict__ out)                  // [S*B*H | h_f | c_f]
{
  __shared__ char lds[147456];
  char* ldsW = lds;            // 128KB [ct:8][ks:16][ke:4][r:16][16B]
  char* ldsH = lds + 131072;   // 16KB  [ke:4][b:16][slot:16][16B], slot=(ks^b)&15

  const int tid  = threadIdx.x;
  const int lane = tid & 63;
  const int wave = tid >> 6;          // 0..7 == tile ct
  const int q    = blockIdx.x >> 4;   // batch quad
  const int ublk = blockIdx.x & 15;   // unit 32-block

  // --- stage W tile into LDS (once): tile-row r -> (du = r>>2, gate = r&3) ---
  for (int c = tid; c < 8192; c += 512) {
    int ct2 = c >> 10, r6 = c & 1023;
    int ks = r6 >> 6, ke = (r6 >> 4) & 3, r = r6 & 15;
    long row = (long)(r & 3) * 512 + ublk * 32 + ct2 * 4 + (r >> 2);
    *(short8v*)(ldsW + c * 16) =
        *(const short8v*)(WhhB + row * 512 + ks * 32 + ke * 8);
  }
  __syncthreads();

  // gather assignment: thread stages 16 tagged units for one batch row (64B)
  const int gb  = tid >> 5;           // 0..15 (batch row staged)
  const int us  = tid & 31;           // 0..31 (16-unit segment)
  const int gks = us >> 1;            // k-step (32 units)
  const int keh = us & 1;             // which 16-unit half

  // cell assignment: one cell per lane, tile ct = wave
  const int ct  = wave;
  const int b_c = lane & 15;
  const int duc = lane >> 4;
  const int b_g = q * 16 + b_c;
  const int u_g = ublk * 32 + ct * 4 + duc;

  float cst = 0.f;
  float heat = (float)tid * 1e-3f + 1.0f;

  #pragma unroll 1
  for (int t = 0; t < S_LEN; ++t) {
    // x-gates (8B, i/f/g/o contiguous) — issued before the poll, hides under it
    ushort4 pv = *(const ushort4*)(pre + (((long)t * 512 + u_g) * 64 + b_g) * 4);

    if (t > 0) {
      // discovery: 16 flags, 1 dword per lane (own block exempt)
      {
        const unsigned* fp = &flags[q * 16 + (lane & 15)];
        while (true) {
          unsigned v = ((lane & 15) == ublk) ? 0xffffffffu
                     : __hip_atomic_load(fp, __ATOMIC_RELAXED, __HIP_MEMORY_SCOPE_AGENT);
          if (__all(v >= (unsigned)t)) break;
          #pragma unroll
          for (int z = 0; z < 8; ++z) heat = __builtin_fmaf(heat, 1.000001f, 1e-6f);
          asm volatile("" : "+v"(heat));
        }
      }
      asm volatile("" ::: "memory");
      // one-shot gather of 16 tagged words, VALIDATED (retry only on the rare
      // flag-beats-data reorder window — the r13 silent race, now bounded)
      const unsigned* hb = hbuf + (t & 1) * (64 * 512)
                         + (q * 16 + gb) * 512 + us * 16;
      const unsigned tg = (unsigned)t & 0xffffu;
      unsigned w[16];
      while (true) {
        #pragma unroll
        for (int j = 0; j < 16; ++j)
          w[j] = __hip_atomic_load(hb + j, __ATOMIC_RELAXED, __HIP_MEMORY_SCOPE_AGENT);
        unsigned bad = 0;
        #pragma unroll
        for (int j = 0; j < 16; ++j) bad |= (w[j] ^ tg) & 0xffffu;
        if (__all(bad == 0)) break;
      }
      // pack hi16 payloads -> bf16-pair dwords; 2 swizzled b128 LDS writes
      char* hp = ldsH + gb * 256 + ((gks ^ gb) & 15) * 16;
      uint4v d0, d1;
      #pragma unroll
      for (int j = 0; j < 4; ++j) {
        d0[j] = (w[2 * j]     >> 16) | (w[2 * j + 1] & 0xffff0000u);
        d1[j] = (w[8 + 2 * j] >> 16) | (w[8 + 2 * j + 1] & 0xffff0000u);
      }
      *(uint4v*)(hp + (keh * 2 + 0) * 4096) = d0;
      *(uint4v*)(hp + (keh * 2 + 1) * 4096) = d1;
    }

    // barrier #1: H tile ready (LDS-only drain)
    asm volatile("s_waitcnt lgkmcnt(0)" ::: "memory");
    __builtin_amdgcn_s_barrier();
    __builtin_amdgcn_sched_barrier(0);

    f32x4 sum = (f32x4){0.f, 0.f, 0.f, 0.f};
    if (t > 0) {
      f32x4 e0 = sum, e1 = sum;
      const char* wa = ldsW + ct * 16384 + (lane >> 4) * 256 + (lane & 15) * 16;
      const char* ha = ldsH + (lane >> 4) * 4096 + (lane & 15) * 256;
      const int bcol = lane & 15;
      #pragma unroll
      for (int ks = 0; ks < 16; ++ks) {
        short8v av = *(const short8v*)(wa + ks * 1024);               // W (A-op)
        short8v bv = *(const short8v*)(ha + ((ks ^ bcol) & 15) * 16); // h (B-op)
        if (ks & 1) e1 = __builtin_amdgcn_mfma_f32_16x16x32_bf16(av, bv, e1, 0, 0, 0);
        else        e0 = __builtin_amdgcn_mfma_f32_16x16x32_bf16(av, bv, e0, 0, 0, 0);
      }
      sum = e0 + e1;
    }

    // barrier #2: ldsH reads of step t done -> next staging may overwrite
    asm volatile("s_waitcnt lgkmcnt(0)" ::: "memory");
    __builtin_amdgcn_s_barrier();
    __builtin_amdgcn_sched_barrier(0);

    // cell update fully in-register: sum[0..3] = (i,f,g,o)
    float zi = sum[0] + bf2f(pv.x);
    float zf = sum[1] + bf2f(pv.y);
    float zg = sum[2] + bf2f(pv.z);
    float zo = sum[3] + bf2f(pv.w);
    float ii = 1.f / (1.f + __expf(-zi));
    float ff = 1.f / (1.f + __expf(-zf));
    float e1x = __expf(2.f * fminf(zg, 15.f));
    float gg = (e1x - 1.f) / (e1x + 1.f);
    float oo = 1.f / (1.f + __expf(-zo));
    float cn = ff * cst + ii * gg;
    float e2x = __expf(2.f * fminf(cn, 15.f));
    float tc = (e2x - 1.f) / (e2x + 1.f);
    float hv = oo * tc;
    cst = cn;

    // tagged publish: one dword per lane (payload + step tag, self-validating)
    unsigned hw = ((unsigned)f2bf(hv) << 16) | ((unsigned)(t + 1) & 0xffffu);
    __hip_atomic_store(hbuf + ((t + 1) & 1) * (64 * 512) + b_g * 512 + u_g,
                       hw, __ATOMIC_RELAXED, __HIP_MEMORY_SCOPE_AGENT);

    // release: drain h stores, then publish flag (fast-path discovery)
    asm volatile("s_waitcnt vmcnt(0)" ::: "memory");
    __syncthreads();
    if (tid == 0)
      __hip_atomic_store(&flags[q * 16 + ublk], (unsigned)(t + 1),
                         __ATOMIC_RELAXED, __HIP_MEMORY_SCOPE_AGENT);

    // out stores AFTER flag publish: off the critical path
    out[(long)t * (BATCH * HID) + (long)b_g * HID + u_g] = hv;
    if (t == S_LEN - 1) {
      long fb = (long)S_LEN * (BATCH * HID);
      out[fb + (long)b_g * HID + u_g] = hv;
      out[fb + BATCH * HID + (long)b_g * HID + u_g] = cn;
    }
  }
}

extern "C" void kernel_launch(void* const* d_in, const int* in_sizes, int n_in,
                              void* d_out, int out_size, void* d_ws, size_t ws_size,
                              hipStream_t stream) {
  const float* x   = (const float*)d_in[0];
  const float* Wih = (const float*)d_in[1];
  const float* Whh = (const float*)d_in[2];
  const float* bih = (const float*)d_in[3];
  const float* bhh = (const float*)d_in[4];
  float* out = (float*)d_out;

  char* ws = (char*)d_ws;
  size_t off = 0;
  auto alloc = [&](size_t bytes) -> char* {
    char* p = ws + off;
    off += (bytes + 255) & ~(size_t)255;
    return p;
  };
  unsigned short* xhi  = (unsigned short*)alloc((size_t)S_LEN * BATCH * DIN * 2);
  unsigned short* xlo  = (unsigned short*)alloc((size_t)S_LEN * BATCH * DIN * 2);
  unsigned short* preb = (unsigned short*)alloc((size_t)S_LEN * GATES * BATCH * 2);
  unsigned short* WihB = (unsigned short*)alloc((size_t)GATES * DIN * 2);
  unsigned short* WhhB = (unsigned short*)alloc((size_t)GATES * DIN * 2);
  float*          bias = (float*)alloc((size_t)GATES * 4);
  unsigned*       hbuf = (unsigned*)alloc((size_t)2 * BATCH * HID * 4);  // 256KB tagged
  unsigned*       flg  = (unsigned*)alloc((size_t)4 * 16 * 4);

  // replay-safe: clear tags + flags every launch
  hipMemsetAsync(hbuf, 0, (size_t)2 * BATCH * HID * 4, stream);
  hipMemsetAsync(flg, 0, (size_t)4 * 16 * 4, stream);
  k_split_x<<<8192, 256, 0, stream>>>(x, xhi, xlo);
  k_prep_w<<<4096, 256, 0, stream>>>(Wih, Whh, bih, bhh, WihB, WhhB, bias);
  k_gemm_pre<<<16384, 256, 0, stream>>>(WihB, xhi, xlo, bias, preb);
  k_lstm<<<64, 512, 0, stream>>>(preb, WhhB, hbuf, flg, out);
}

// Round 15
// 9051.098 us; speedup vs baseline: 6.2461x; 1.7249x over previous
//
#include <hip/hip_runtime.h>
#include <hip/hip_bf16.h>

#define S_LEN 2048
#define BATCH 64
#define HID   512
#define GATES 2048   // 4*HID
#define DIN   512

typedef __attribute__((ext_vector_type(8))) short short8v;
typedef __attribute__((ext_vector_type(4))) float f32x4;
typedef __attribute__((ext_vector_type(4))) unsigned uint4v;

__device__ inline unsigned short f2bf(float f) {
  union { float f; unsigned u; } a; a.f = f;
  unsigned r = a.u + 0x7fffu + ((a.u >> 16) & 1u);
  return (unsigned short)(r >> 16);
}
__device__ inline float bf2f(unsigned short h) {
  union { unsigned u; float f; } a; a.u = ((unsigned)h) << 16; return a.f;
}

// ---------- kernel 1: split x (fp32) -> bf16 hi + lo ----------
__global__ __launch_bounds__(256) void k_split_x(const float* __restrict__ x,
                                                 unsigned short* __restrict__ xhi,
                                                 unsigned short* __restrict__ xlo) {
  const long total = (long)S_LEN * BATCH * DIN / 4;
  long i = (long)blockIdx.x * blockDim.x + threadIdx.x;
  const long stride = (long)gridDim.x * blockDim.x;
  for (; i < total; i += stride) {
    float4 v = ((const float4*)x)[i];
    ushort4 hv, lv;
    hv.x = f2bf(v.x); lv.x = f2bf(v.x - bf2f(hv.x));
    hv.y = f2bf(v.y); lv.y = f2bf(v.y - bf2f(hv.y));
    hv.z = f2bf(v.z); lv.z = f2bf(v.z - bf2f(hv.z));
    hv.w = f2bf(v.w); lv.w = f2bf(v.w - bf2f(hv.w));
    ((ushort4*)xhi)[i] = hv;
    ((ushort4*)xlo)[i] = lv;
  }
}

// ---------- kernel 2: weights -> bf16, bias sum ----------
__global__ __launch_bounds__(256) void k_prep_w(const float* __restrict__ Wih,
                                                const float* __restrict__ Whh,
                                                const float* __restrict__ bih,
                                                const float* __restrict__ bhh,
                                                unsigned short* __restrict__ WihB,
                                                unsigned short* __restrict__ WhhB,
                                                float* __restrict__ bias) {
  int i = blockIdx.x * 256 + threadIdx.x;
  if (i < GATES * DIN) {
    WihB[i] = f2bf(Wih[i]);
    WhhB[i] = f2bf(Whh[i]);
  }
  if (i < GATES) bias[i] = bih[i] + bhh[i];
}

// ---------- kernel 3: pre[t][u][b][gate] = x[t,b,:]·Wih[gate*512+u,:] + biases ----------
#define BM 128
#define BN 128
#define BK 32
#define LDSROW 40

__global__ __launch_bounds__(256) void k_gemm_pre(
    const unsigned short* __restrict__ A,   // WihB [2048][512]
    const unsigned short* __restrict__ Bh,  // xhi  [131072][512]
    const unsigned short* __restrict__ Bl,  // xlo
    const float* __restrict__ bias,
    unsigned short* __restrict__ pre)       // [S][512 u][64 b][4 gate] bf16
{
  __shared__ unsigned short As [BM * LDSROW];
  __shared__ unsigned short Bhs[BM * LDSROW];
  __shared__ unsigned short Bls[BM * LDSROW];

  const int tid  = threadIdx.x;
  const int lane = tid & 63;
  const int wave = tid >> 6;
  const int bm = blockIdx.x & 15;
  const int bn = blockIdx.x >> 4;
  const int wr = wave >> 1, wc = wave & 1;

  f32x4 acc[4][4];
  #pragma unroll
  for (int i = 0; i < 4; ++i)
    #pragma unroll
    for (int j = 0; j < 4; ++j) acc[i][j] = (f32x4){0.f, 0.f, 0.f, 0.f};

  const long arow0 = (long)bm * BM;
  const long brow0 = (long)bn * BN;

  for (int kt = 0; kt < DIN / BK; ++kt) {
    #pragma unroll
    for (int it = 0; it < 2; ++it) {
      int c = tid + it * 256;
      int row = c >> 2, kc = c & 3;
      int lbyte = row * (LDSROW * 2) + kc * 16;
      long ga = (arow0 + row) * 512 + kt * BK + kc * 8;
      long gb = (brow0 + row) * 512 + kt * BK + kc * 8;
      *(short8v*)((char*)As  + lbyte) = *(const short8v*)(A  + ga);
      *(short8v*)((char*)Bhs + lbyte) = *(const short8v*)(Bh + gb);
      *(short8v*)((char*)Bls + lbyte) = *(const short8v*)(Bl + gb);
    }
    __syncthreads();

    short8v a[4], bh[4], bl[4];
    #pragma unroll
    for (int mt = 0; mt < 4; ++mt) {
      int r = wr * 64 + mt * 16 + (lane & 15);
      a[mt] = *(const short8v*)((const char*)As + r * (LDSROW * 2) + (lane >> 4) * 16);
    }
    #pragma unroll
    for (int nt = 0; nt < 4; ++nt) {
      int r = wc * 64 + nt * 16 + (lane & 15);
      bh[nt] = *(const short8v*)((const char*)Bhs + r * (LDSROW * 2) + (lane >> 4) * 16);
      bl[nt] = *(const short8v*)((const char*)Bls + r * (LDSROW * 2) + (lane >> 4) * 16);
    }
    #pragma unroll
    for (int mt = 0; mt < 4; ++mt)
      #pragma unroll
      for (int nt = 0; nt < 4; ++nt) {
        acc[mt][nt] = __builtin_amdgcn_mfma_f32_16x16x32_bf16(a[mt], bh[nt], acc[mt][nt], 0, 0, 0);
        acc[mt][nt] = __builtin_amdgcn_mfma_f32_16x16x32_bf16(a[mt], bl[nt], acc[mt][nt], 0, 0, 0);
      }
    __syncthreads();
  }

  #pragma unroll
  for (int mt = 0; mt < 4; ++mt) {
    #pragma unroll
    for (int j = 0; j < 4; ++j) {
      int m = bm * BM + wr * 64 + mt * 16 + (lane >> 4) * 4 + j;
      int gate = m >> 9;
      int u    = m & 511;
      float bv = bias[m];
      #pragma unroll
      for (int nt = 0; nt < 4; ++nt) {
        int n = bn * BN + wc * 64 + nt * 16 + (lane & 15);
        int t = n >> 6, b = n & 63;
        pre[(((long)t * 512 + u) * 64 + b) * 4 + gate] = f2bf(acc[mt][nt][j] + bv);
      }
    }
  }
}

// ---------- kernel 4: persistent recurrence, u64-tagged verified gather ----------
// r13 machine (64 blocks x 512 threads, 8 gate-complete tiles, W_hh 128KB LDS,
// swizzled ldsH, drain+syncthreads+flag discovery) with r14's correctness at
// r13's packet economy:
//  * h words are u64 = (packed 2xbf16)<<32 | step. An 8B store lands atomically
//    in its cache line -> any read width sees each {payload,tag} consistently.
//  * publish: 256 u64 atomic stores/block (r13 count; r14 had 512 dwords).
//  * gather: FIRST TRY = 4 plain 16B loads (r13's 4 packets; L1/L2 staleness
//    is CAUGHT by tags instead of trusted); RETRY = 8 agent-atomic u64 loads
//    (the empirically-coherent path) -> guaranteed progress.
//  * steady state: flag was published after vmcnt-drain + __syncthreads, so
//    validation passes on try 1 -> cost == r13 + tag bytes.
__global__ __launch_bounds__(512, 1) void k_lstm(
    const unsigned short* __restrict__ pre,   // [S][512][64][4] bf16
    const unsigned short* __restrict__ WhhB,  // [2048][512] bf16
    unsigned long long* __restrict__ hbuf,    // [2][64 b][256] u64 (2 units | tag)
    unsigned* __restrict__ flags,             // [4][16]
    float* __restrict__ out)                  // [S*B*H | h_f | c_f]
{
  __shared__ char lds[147456];
  char* ldsW = lds;            // 128KB [ct:8][ks:16][ke:4][r:16][16B]
  char* ldsH = lds + 131072;   // 16KB  [ke:4][b:16][slot:16][16B], slot=(ks^b)&15

  const int tid  = threadIdx.x;
  const int lane = tid & 63;
  const int wave = tid >> 6;          // 0..7 == tile ct
  const int q    = blockIdx.x >> 4;   // batch quad
  const int ublk = blockIdx.x & 15;   // unit 32-block

  // --- stage W tile into LDS (once): tile-row r -> (du = r>>2, gate = r&3) ---
  for (int c = tid; c < 8192; c += 512) {
    int ct2 = c >> 10, r6 = c & 1023;
    int ks = r6 >> 6, ke = (r6 >> 4) & 3, r = r6 & 15;
    long row = (long)(r & 3) * 512 + ublk * 32 + ct2 * 4 + (r >> 2);
    *(short8v*)(ldsW + c * 16) =
        *(const short8v*)(WhhB + row * 512 + ks * 32 + ke * 8);
  }
  __syncthreads();

  // gather assignment: thread stages 16 units (8 tagged u64, 64B) for one row
  const int gb  = tid >> 5;           // 0..15 (batch row staged)
  const int us  = tid & 31;           // 0..31
  const int gks = us >> 1;            // k-step (32 units)
  const int keh = us & 1;             // which 16-unit half

  // cell assignment: one cell per lane, tile ct = wave
  const int ct  = wave;
  const int b_c = lane & 15;
  const int duc = lane >> 4;
  const int b_g = q * 16 + b_c;
  const int u_g = ublk * 32 + ct * 4 + duc;

  float cst = 0.f;
  float heat = (float)tid * 1e-3f + 1.0f;

  #pragma unroll 1
  for (int t = 0; t < S_LEN; ++t) {
    // x-gates (8B, i/f/g/o contiguous) — issued before the poll, hides under it
    ushort4 pv = *(const ushort4*)(pre + (((long)t * 512 + u_g) * 64 + b_g) * 4);

    if (t > 0) {
      // discovery: 16 flags, 1 dword per lane (own block exempt)
      {
        const unsigned* fp = &flags[q * 16 + (lane & 15)];
        while (true) {
          unsigned v = ((lane & 15) == ublk) ? 0xffffffffu
                     : __hip_atomic_load(fp, __ATOMIC_RELAXED, __HIP_MEMORY_SCOPE_AGENT);
          if (__all(v >= (unsigned)t)) break;
          #pragma unroll
          for (int z = 0; z < 8; ++z) heat = __builtin_fmaf(heat, 1.000001f, 1e-6f);
          asm volatile("" : "+v"(heat));
        }
      }
      asm volatile("" ::: "memory");

      const unsigned long long* hb = hbuf + (t & 1) * (64 * 256)
                                   + (q * 16 + gb) * 256 + gks * 16 + keh * 8;
      const unsigned tg = (unsigned)t;
      unsigned long long w[8];
      // first try: 4 plain 16B loads (r13 packet count; tags catch staleness)
      {
        ulonglong2 v0 = *(const ulonglong2*)(hb + 0);
        ulonglong2 v1 = *(const ulonglong2*)(hb + 2);
        ulonglong2 v2 = *(const ulonglong2*)(hb + 4);
        ulonglong2 v3 = *(const ulonglong2*)(hb + 6);
        w[0] = v0.x; w[1] = v0.y; w[2] = v1.x; w[3] = v1.y;
        w[4] = v2.x; w[5] = v2.y; w[6] = v3.x; w[7] = v3.y;
      }
      while (true) {
        unsigned bad = 0;
        #pragma unroll
        for (int j = 0; j < 8; ++j) bad |= ((unsigned)w[j]) ^ tg;
        if (__all(bad == 0)) break;
        // retry: coherent agent-atomic path (L1/L2-bypassing, proven fresh)
        #pragma unroll
        for (int j = 0; j < 8; ++j)
          w[j] = __hip_atomic_load(hb + j, __ATOMIC_RELAXED, __HIP_MEMORY_SCOPE_AGENT);
      }
      // payload = hi32 of each u64 (2 packed bf16 units); 2 swizzled b128 writes
      char* hp = ldsH + gb * 256 + ((gks ^ gb) & 15) * 16;
      uint4v d0, d1;
      #pragma unroll
      for (int j = 0; j < 4; ++j) {
        d0[j] = (unsigned)(w[j]     >> 32);
        d1[j] = (unsigned)(w[4 + j] >> 32);
      }
      *(uint4v*)(hp + (keh * 2 + 0) * 4096) = d0;
      *(uint4v*)(hp + (keh * 2 + 1) * 4096) = d1;
    }

    // barrier #1: H tile ready (LDS-only drain)
    asm volatile("s_waitcnt lgkmcnt(0)" ::: "memory");
    __builtin_amdgcn_s_barrier();
    __builtin_amdgcn_sched_barrier(0);

    f32x4 sum = (f32x4){0.f, 0.f, 0.f, 0.f};
    if (t > 0) {
      f32x4 e0 = sum, e1 = sum;
      const char* wa = ldsW + ct * 16384 + (lane >> 4) * 256 + (lane & 15) * 16;
      const char* ha = ldsH + (lane >> 4) * 4096 + (lane & 15) * 256;
      const int bcol = lane & 15;
      #pragma unroll
      for (int ks = 0; ks < 16; ++ks) {
        short8v av = *(const short8v*)(wa + ks * 1024);               // W (A-op)
        short8v bv = *(const short8v*)(ha + ((ks ^ bcol) & 15) * 16); // h (B-op)
        if (ks & 1) e1 = __builtin_amdgcn_mfma_f32_16x16x32_bf16(av, bv, e1, 0, 0, 0);
        else        e0 = __builtin_amdgcn_mfma_f32_16x16x32_bf16(av, bv, e0, 0, 0, 0);
      }
      sum = e0 + e1;
    }

    // barrier #2: ldsH reads of step t done -> next staging may overwrite
    asm volatile("s_waitcnt lgkmcnt(0)" ::: "memory");
    __builtin_amdgcn_s_barrier();
    __builtin_amdgcn_sched_barrier(0);

    // cell update fully in-register: sum[0..3] = (i,f,g,o)
    float zi = sum[0] + bf2f(pv.x);
    float zf = sum[1] + bf2f(pv.y);
    float zg = sum[2] + bf2f(pv.z);
    float zo = sum[3] + bf2f(pv.w);
    float ii = 1.f / (1.f + __expf(-zi));
    float ff = 1.f / (1.f + __expf(-zf));
    float e1x = __expf(2.f * fminf(zg, 15.f));
    float gg = (e1x - 1.f) / (e1x + 1.f);
    float oo = 1.f / (1.f + __expf(-zo));
    float cn = ff * cst + ii * gg;
    float e2x = __expf(2.f * fminf(cn, 15.f));
    float tc = (e2x - 1.f) / (e2x + 1.f);
    float hv = oo * tc;
    cst = cn;

    // tagged publish: pair lanes pack 2 units + step tag into one u64 store
    {
      unsigned short h16 = f2bf(hv);
      unsigned prt = (unsigned)__shfl_xor((int)(unsigned)h16, 16);
      if (!(lane & 16)) {   // duc even: lo16 = unit u, hi16 = unit u+1
        unsigned payload = (unsigned)h16 | (prt << 16);
        unsigned long long w64 = ((unsigned long long)payload << 32)
                               | (unsigned)(t + 1);
        __hip_atomic_store(hbuf + ((t + 1) & 1) * (64 * 256) + b_g * 256
                               + ublk * 16 + ct * 2 + (duc >> 1),
                           w64, __ATOMIC_RELAXED, __HIP_MEMORY_SCOPE_AGENT);
      }
    }

    // release: drain h stores, then publish flag (fast-path discovery)
    asm volatile("s_waitcnt vmcnt(0)" ::: "memory");
    __syncthreads();
    if (tid == 0)
      __hip_atomic_store(&flags[q * 16 + ublk], (unsigned)(t + 1),
                         __ATOMIC_RELAXED, __HIP_MEMORY_SCOPE_AGENT);

    // out stores AFTER flag publish: off the critical path
    out[(long)t * (BATCH * HID) + (long)b_g * HID + u_g] = hv;
    if (t == S_LEN - 1) {
      long fb = (long)S_LEN * (BATCH * HID);
      out[fb + (long)b_g * HID + u_g] = hv;
      out[fb + BATCH * HID + (long)b_g * HID + u_g] = cn;
    }
  }
}

extern "C" void kernel_launch(void* const* d_in, const int* in_sizes, int n_in,
                              void* d_out, int out_size, void* d_ws, size_t ws_size,
                              hipStream_t stream) {
  const float* x   = (const float*)d_in[0];
  const float* Wih = (const float*)d_in[1];
  const float* Whh = (const float*)d_in[2];
  const float* bih = (const float*)d_in[3];
  const float* bhh = (const float*)d_in[4];
  float* out = (float*)d_out;

  char* ws = (char*)d_ws;
  size_t off = 0;
  auto alloc = [&](size_t bytes) -> char* {
    char* p = ws + off;
    off += (bytes + 255) & ~(size_t)255;
    return p;
  };
  unsigned short*     xhi  = (unsigned short*)alloc((size_t)S_LEN * BATCH * DIN * 2);
  unsigned short*     xlo  = (unsigned short*)alloc((size_t)S_LEN * BATCH * DIN * 2);
  unsigned short*     preb = (unsigned short*)alloc((size_t)S_LEN * GATES * BATCH * 2);
  unsigned short*     WihB = (unsigned short*)alloc((size_t)GATES * DIN * 2);
  unsigned short*     WhhB = (unsigned short*)alloc((size_t)GATES * DIN * 2);
  float*              bias = (float*)alloc((size_t)GATES * 4);
  unsigned long long* hbuf = (unsigned long long*)alloc((size_t)2 * 64 * 256 * 8); // 256KB
  unsigned*           flg  = (unsigned*)alloc((size_t)4 * 16 * 4);

  // replay-safe: clear tags + flags every launch
  hipMemsetAsync(hbuf, 0, (size_t)2 * 64 * 256 * 8, stream);
  hipMemsetAsync(flg, 0, (size_t)4 * 16 * 4, stream);
  k_split_x<<<8192, 256, 0, stream>>>(x, xhi, xlo);
  k_prep_w<<<4096, 256, 0, stream>>>(Wih, Whh, bih, bhh, WihB, WhhB, bias);
  k_gemm_pre<<<16384, 256, 0, stream>>>(WihB, xhi, xlo, bias, preb);
  k_lstm<<<64, 512, 0, stream>>>(preb, WhhB, hbuf, flg, out);
}